// Round 4
// baseline (939.865 us; speedup 1.0000x reference)
//
#include <hip/hip_runtime.h>
#include <hip/hip_cooperative_groups.h>
#include <math.h>

namespace cg = cooperative_groups;

#define N_NODES 10000
#define E_EDGES 320000
#define IN_DIM 128
#define EMB 128
#define HID 64
#define NEG_SLOPE 0.2f

#define COOP_BLOCKS 1024
#define DG_BLOCKS 625          // dense_gat: 625 * 16 rows = 10000

typedef __attribute__((ext_vector_type(8))) short short8;     // 8 bf16 (4 VGPR)
typedef __attribute__((ext_vector_type(4))) short short4_t;   // 4 bf16
typedef __attribute__((ext_vector_type(4))) float floatx4;    // 4 fp32
typedef __attribute__((ext_vector_type(4))) int   intx4;
typedef __attribute__((ext_vector_type(2))) int   intx2;

// fp32 -> bf16 bits, round-to-nearest-even
__device__ __forceinline__ short f2bf(float f) {
    unsigned u = __float_as_uint(f);
    unsigned r = u + 0x7fffu + ((u >> 16) & 1u);
    return (short)(r >> 16);
}

__device__ __forceinline__ float sigmoidf_fast(float v) {
    return __builtin_amdgcn_rcpf(1.f + __expf(-v));
}

// ---------------------------------------------------------------------------
// Shared device bodies (used by both the fused cooperative kernel and the
// separate-kernel fallback).
// ---------------------------------------------------------------------------
__device__ __forceinline__ void dense_gat_body(
    float* __restrict__ smem,            // >= 8192 floats (32 KB)
    int row0, int t,
    const float* __restrict__ x, const float* __restrict__ dw,
    const float* __restrict__ db, const float* __restrict__ gw,
    const float* __restrict__ asv, const float* __restrict__ adv,
    float* __restrict__ z, float* __restrict__ a_src, float* __restrict__ a_dst)
{
    float* const xs  = smem;             // [16][128]
    float* const hs  = smem + 2048;      // [16][128]
    float* const wsm = smem + 4096;      // [32*128] / [64*64]

    #pragma unroll
    for (int r = 0; r < 2; ++r) {
        const int idx = t + r * 256;           // 0..511 float4 slots
        const int row = idx >> 5, c4 = idx & 31;
        *(floatx4*)&xs[row * 128 + c4 * 4] =
            *(const floatx4*)&x[(row0 + row) * IN_DIM + c4 * 4];
    }

    // GEMM1: col = t&127, rows (t>>7)*8 .. +8
    const int col = t & 127, rb = (t >> 7) * 8;
    float acc[8];
    {
        const float bias = db[col];
        #pragma unroll
        for (int r = 0; r < 8; ++r) acc[r] = bias;
    }
    for (int ch = 0; ch < 4; ++ch) {
        __syncthreads();                       // xs ready (ch=0) / wsm reads done
        #pragma unroll
        for (int r = 0; r < 4; ++r) {          // stage dw[ch*32..+32][0..128]
            const int idx = t + r * 256;
            const int row = idx >> 5, c4 = idx & 31;
            *(floatx4*)&wsm[row * 128 + c4 * 4] =
                *(const floatx4*)&dw[(ch * 32 + row) * EMB + c4 * 4];
        }
        __syncthreads();
        #pragma unroll
        for (int jg = 0; jg < 8; ++jg) {
            const int jb = jg * 4;
            floatx4 xr[8];
            #pragma unroll
            for (int r = 0; r < 8; ++r)
                xr[r] = *(const floatx4*)&xs[(rb + r) * 128 + ch * 32 + jb];
            float wv[4];
            #pragma unroll
            for (int k = 0; k < 4; ++k) wv[k] = wsm[(jb + k) * 128 + col];
            #pragma unroll
            for (int k = 0; k < 4; ++k)
                #pragma unroll
                for (int r = 0; r < 8; ++r) acc[r] = fmaf(xr[r][k], wv[k], acc[r]);
        }
    }
    #pragma unroll
    for (int r = 0; r < 8; ++r) hs[(rb + r) * 128 + col] = fmaxf(acc[r], 0.f);

    // GEMM2: col2 = t&63, rows (t>>6)*4 .. +4
    const int col2 = t & 63, rb2 = (t >> 6) * 4;
    float acc2[4] = {0.f, 0.f, 0.f, 0.f};
    for (int ch = 0; ch < 2; ++ch) {
        __syncthreads();                       // hs ready / wsm reads done
        #pragma unroll
        for (int r = 0; r < 4; ++r) {          // stage gw[ch*64..+64][0..64]
            const int idx = t + r * 256;
            const int row = idx >> 4, c4 = idx & 15;
            *(floatx4*)&wsm[row * 64 + c4 * 4] =
                *(const floatx4*)&gw[(ch * 64 + row) * HID + c4 * 4];
        }
        __syncthreads();
        #pragma unroll
        for (int kg = 0; kg < 16; ++kg) {
            const int kb = kg * 4;
            floatx4 hr[4];
            #pragma unroll
            for (int r = 0; r < 4; ++r)
                hr[r] = *(const floatx4*)&hs[(rb2 + r) * 128 + ch * 64 + kb];
            float gv[4];
            #pragma unroll
            for (int k = 0; k < 4; ++k) gv[k] = wsm[(kb + k) * 64 + col2];
            #pragma unroll
            for (int k = 0; k < 4; ++k)
                #pragma unroll
                for (int r = 0; r < 4; ++r) acc2[r] = fmaf(hr[r][k], gv[k], acc2[r]);
        }
    }

    // store z + fused attention dot products (wave holds full row of 64 cols)
    const float as_c = asv[col2], ad_c = adv[col2];
    #pragma unroll
    for (int r = 0; r < 4; ++r) {
        z[(row0 + rb2 + r) * HID + col2] = acc2[r];
        float ps = acc2[r] * as_c;
        float pd = acc2[r] * ad_c;
        #pragma unroll
        for (int off = 32; off > 0; off >>= 1) {
            ps += __shfl_down(ps, off, 64);
            pd += __shfl_down(pd, off, 64);
        }
        if ((t & 63) == 0) {
            a_src[row0 + rb2 + r] = ps;
            a_dst[row0 + rb2 + r] = pd;
        }
    }
}

__device__ __forceinline__ void count_body(
    int tid, int nth, const int* __restrict__ ei, int* __restrict__ cnt)
{
    const int total = E_EDGES + N_NODES;
    for (int e = tid; e < total; e += nth) {
        int s, d;
        if (e < E_EDGES) { s = ei[e]; d = ei[E_EDGES + e]; }
        else             { s = d = e - E_EDGES; }
        if ((unsigned)s >= N_NODES || (unsigned)d >= N_NODES) continue;
        atomicAdd(&cnt[d], 1);
    }
}

// 256 threads, 40 items each; register-resident values, LDS only for partials.
__device__ __forceinline__ void scan_body(
    int* __restrict__ part, int t,
    const int* __restrict__ cnt, int* __restrict__ offs, int* __restrict__ cursor)
{
    const int base = t * 40;
    int vals[40];
    int local = 0;
    #pragma unroll
    for (int i = 0; i < 40; ++i) {
        const int idx = base + i;
        const int c = (idx < N_NODES) ? cnt[idx] : 0;
        vals[i] = c;
        local += c;
    }
    part[t] = local;
    __syncthreads();
    for (int off = 1; off < 256; off <<= 1) {   // Hillis-Steele inclusive
        const int v = (t >= off) ? part[t - off] : 0;
        __syncthreads();
        part[t] += v;
        __syncthreads();
    }
    int running = (t == 0) ? 0 : part[t - 1];   // exclusive base
    #pragma unroll
    for (int i = 0; i < 40; ++i) {
        const int idx = base + i;
        if (idx < N_NODES) { offs[idx] = running; cursor[idx] = running; }
        running += vals[i];
    }
    if (t == 255) offs[N_NODES] = running;
}

__device__ __forceinline__ void scatter_body(
    int tid, int nth, const int* __restrict__ ei,
    const float* __restrict__ a_src, const float* __restrict__ a_dst,
    int* __restrict__ cursor, intx2* __restrict__ se)
{
    const int total = E_EDGES + N_NODES;
    for (int e = tid; e < total; e += nth) {
        int s, d;
        if (e < E_EDGES) { s = ei[e]; d = ei[E_EDGES + e]; }
        else             { s = d = e - E_EDGES; }
        if ((unsigned)s >= N_NODES || (unsigned)d >= N_NODES) continue;
        float v = a_src[s] + a_dst[d];
        v = (v > 0.f) ? v : NEG_SLOPE * v;
        const float w = __expf(v);      // max-shift skipped: |v| small, fp32 safe
        const int pos = atomicAdd(&cursor[d], 1);
        intx2 p;
        p[0] = s;
        p[1] = __float_as_int(w);
        se[pos] = p;
    }
}

// one wave per node; 4 edges in flight (16 lanes x float4 each).
__device__ __forceinline__ void aggregate_body(
    int wid, int lane, const int* __restrict__ offs, const intx2* __restrict__ se,
    const float* __restrict__ z, const float* __restrict__ gb,
    float* __restrict__ emb)
{
    const int g  = lane >> 4;            // edge subgroup 0..3
    const int c4 = (lane & 15) * 4;      // feature slot
    const int beg = offs[wid], end = offs[wid + 1];
    floatx4 acc = {0.f, 0.f, 0.f, 0.f};
    float sw = 0.f;
    for (int i = beg + g; i < end; i += 4) {
        const intx2 p = se[i];                                // broadcast in group
        const floatx4 zv = *(const floatx4*)&z[p[0] * HID + c4];
        const float w = __int_as_float(p[1]);
        acc += zv * w;
        sw  += w;
    }
    #pragma unroll
    for (int off = 16; off <= 32; off <<= 1) {
        #pragma unroll
        for (int k = 0; k < 4; ++k) acc[k] += __shfl_xor(acc[k], off, 64);
        sw += __shfl_xor(sw, off, 64);
    }
    if (g == 0) {
        const floatx4 gv = *(const floatx4*)&gb[c4];
        floatx4 r;
        #pragma unroll
        for (int k = 0; k < 4; ++k) r[k] = acc[k] / sw + gv[k];
        *(floatx4*)&emb[wid * HID + c4] = r;   // every node has a self loop
    }
}

// ---------------------------------------------------------------------------
// Fused cooperative kernel: (dense_gat || count) -> scan -> scatter -> agg.
// 1024 blocks x 256 thr, 32 KB LDS, VGPR capped for 4 blocks/CU residency.
// Removes 4 launches + full-device drains; count hides under dense_gat.
// ---------------------------------------------------------------------------
__global__ __launch_bounds__(256, 4) void fused_graph_kernel(
    const float* __restrict__ x, const float* __restrict__ dw,
    const float* __restrict__ db, const float* __restrict__ gw,
    const float* __restrict__ asv, const float* __restrict__ adv,
    const int* __restrict__ ei, const float* __restrict__ gb,
    float* __restrict__ z, float* __restrict__ a_src, float* __restrict__ a_dst,
    int* __restrict__ cnt, int* __restrict__ offs, int* __restrict__ cursor,
    intx2* __restrict__ se, float* __restrict__ emb)
{
    __shared__ float smem[8192];         // 32 KB, carved per phase
    cg::grid_group grid = cg::this_grid();
    const int b = blockIdx.x;
    const int t = threadIdx.x;

    // ---- phase 0: dense_gat (blocks 0..624) || count (blocks 625..1023) ----
    if (b < DG_BLOCKS) {
        dense_gat_body(smem, b * 16, t, x, dw, db, gw, asv, adv, z, a_src, a_dst);
    } else {
        const int tid = (b - DG_BLOCKS) * 256 + t;
        count_body(tid, (COOP_BLOCKS - DG_BLOCKS) * 256, ei, cnt);
    }
    grid.sync();

    // ---- phase 1: scan (block 0 only; ~40 KB from L2, register-resident) ----
    if (b == 0) scan_body((int*)smem, t, cnt, offs, cursor);
    grid.sync();

    // ---- phase 2: scatter ----
    scatter_body(b * 256 + t, COOP_BLOCKS * 256, ei, a_src, a_dst, cursor, se);
    grid.sync();

    // ---- phase 3: aggregate, one wave per node, grid-stride ----
    {
        const int lane = t & 63;
        const int wave_glob = (b * 256 + t) >> 6;        // 0..4095
        for (int wid = wave_glob; wid < N_NODES; wid += COOP_BLOCKS * 4)
            aggregate_body(wid, lane, offs, se, z, gb, emb);
    }
}

// ---------------------------------------------------------------------------
// Fallback separate kernels (used only if cooperative launch is unavailable).
// ---------------------------------------------------------------------------
__global__ __launch_bounds__(256) void dense_gat_kernel(
    const float* __restrict__ x, const float* __restrict__ dw,
    const float* __restrict__ db, const float* __restrict__ gw,
    const float* __restrict__ asv, const float* __restrict__ adv,
    float* __restrict__ z, float* __restrict__ a_src, float* __restrict__ a_dst)
{
    __shared__ float smem[8192];
    dense_gat_body(smem, blockIdx.x * 16, threadIdx.x,
                   x, dw, db, gw, asv, adv, z, a_src, a_dst);
}

__global__ __launch_bounds__(256) void count_kernel(
    const int* __restrict__ ei, int* __restrict__ cnt)
{
    count_body(blockIdx.x * blockDim.x + threadIdx.x,
               gridDim.x * blockDim.x, ei, cnt);
}

__global__ __launch_bounds__(256) void scan_kernel(
    const int* __restrict__ cnt, int* __restrict__ offs, int* __restrict__ cursor)
{
    __shared__ int part[256];
    scan_body(part, threadIdx.x, cnt, offs, cursor);
}

__global__ __launch_bounds__(256) void scatter_kernel(
    const int* __restrict__ ei, const float* __restrict__ a_src,
    const float* __restrict__ a_dst, int* __restrict__ cursor,
    intx2* __restrict__ se)
{
    scatter_body(blockIdx.x * blockDim.x + threadIdx.x,
                 gridDim.x * blockDim.x, ei, a_src, a_dst, cursor, se);
}

__global__ __launch_bounds__(256) void aggregate_kernel(
    const int* __restrict__ offs, const intx2* __restrict__ se,
    const float* __restrict__ z, const float* __restrict__ gb,
    float* __restrict__ emb)
{
    const int wid  = (blockIdx.x * blockDim.x + threadIdx.x) >> 6;
    const int lane = threadIdx.x & 63;
    if (wid >= N_NODES) return;
    aggregate_body(wid, lane, offs, se, z, gb, emb);
}

// ---------------------------------------------------------------------------
// Kernel D: sim = sigmoid(emb @ emb^T), SYMMETRIC. Upper-triangle tiles only
// (79*80/2 = 3160 blocks via folded 79x40 grid, bijective). R2 structure
// (best measured): 256 thr, 4 waves of 64x64, sigmoid ONCE into a full-tile
// [128][133] f32 scratch aliased over the bf16 staging buffers, then BOTH
// orientations as >=256B-contiguous float4 runs. NEW: nontemporal stores --
// sim is a 400 MB write-once stream; bypass L2 write-allocate.
// ---------------------------------------------------------------------------
#define SROW 72
#define SCR_STRIDE 133
__global__ __launch_bounds__(256) void sim_kernel(
    const float* __restrict__ emb, float* __restrict__ sim)
{
    __shared__ float smem[128 * SCR_STRIDE];       // 68096 B
    short* const As = (short*)smem;                // [128*72] bf16
    short* const Bs = (short*)smem + 128 * SROW;   // [128*72] bf16
    const int t    = threadIdx.x;
    const int lane = t & 63;
    const int wave = t >> 6;                 // 0..3
    const int wm   = (wave >> 1) * 64;
    const int wn   = (wave & 1) * 64;
    const int l15  = lane & 15;
    const int quad = lane >> 4;              // 0..3

    // upper-tri fold: grid (79, 40) -> (bi <= bj), 3160 blocks exactly
    int bi, bj;
    {
        const int gx = blockIdx.x, gy = blockIdx.y;
        if (gy <= gx) { bi = gy; bj = gx; }                // bi in [0,40)
        else          { bi = 40 + gx; bj = 79 + gx - gy; } // bi in [40,79)
    }

    // ---- stage both row-tiles as bf16 into LDS ----
    #pragma unroll
    for (int round = 0; round < 8; ++round) {
        const int idx = t + round * 256;     // 0..2047
        const int row = idx >> 4, c4 = idx & 15;
        int gr = bi * 128 + row; if (gr > N_NODES - 1) gr = N_NODES - 1;
        int gc = bj * 128 + row; if (gc > N_NODES - 1) gc = N_NODES - 1;
        const floatx4 a = *(const floatx4*)&emb[gr * HID + c4 * 4];
        const floatx4 b = *(const floatx4*)&emb[gc * HID + c4 * 4];
        short4_t sa, sb;
        #pragma unroll
        for (int j = 0; j < 4; ++j) { sa[j] = f2bf(a[j]); sb[j] = f2bf(b[j]); }
        *(short4_t*)&As[row * SROW + c4 * 4] = sa;
        *(short4_t*)&Bs[row * SROW + c4 * 4] = sb;
    }
    __syncthreads();

    // ---- fragments + MFMA (validated layout) ----
    short8 afrag[4][2];
    #pragma unroll
    for (int ti = 0; ti < 4; ++ti)
        #pragma unroll
        for (int ks = 0; ks < 2; ++ks)
            afrag[ti][ks] = *(const short8*)&As[(wm + ti * 16 + l15) * SROW +
                                                ks * 32 + quad * 8];

    floatx4 acc[4][4];
    const floatx4 zero = {0.f, 0.f, 0.f, 0.f};
    #pragma unroll
    for (int ti = 0; ti < 4; ++ti)
        #pragma unroll
        for (int tj = 0; tj < 4; ++tj) acc[ti][tj] = zero;

    #pragma unroll
    for (int tj = 0; tj < 4; ++tj) {
        const short8 bf0 = *(const short8*)&Bs[(wn + tj * 16 + l15) * SROW + quad * 8];
        const short8 bf1 = *(const short8*)&Bs[(wn + tj * 16 + l15) * SROW + 32 + quad * 8];
        #pragma unroll
        for (int ti = 0; ti < 4; ++ti) {
            acc[ti][tj] = __builtin_amdgcn_mfma_f32_16x16x32_bf16(
                afrag[ti][0], bf0, acc[ti][tj], 0, 0, 0);
            acc[ti][tj] = __builtin_amdgcn_mfma_f32_16x16x32_bf16(
                afrag[ti][1], bf1, acc[ti][tj], 0, 0, 0);
        }
    }
    __syncthreads();   // all LDS tile reads done before scratch reuse

    // ---- sigmoid once into full-tile scratch ----
    // C/D layout: row = quad*4+reg (within 16), col = l15
    #pragma unroll
    for (int ti = 0; ti < 4; ++ti)
        #pragma unroll
        for (int reg = 0; reg < 4; ++reg)
            #pragma unroll
            for (int tj = 0; tj < 4; ++tj)
                smem[(wm + ti * 16 + quad * 4 + reg) * SCR_STRIDE +
                     wn + tj * 16 + l15] = sigmoidf_fast(acc[ti][tj][reg]);
    __syncthreads();

    // ---- normal orientation: 128 rows x 512B contiguous float4 runs ----
    #pragma unroll
    for (int round = 0; round < 16; ++round) {
        const int idx = t + round * 256;         // 0..4095
        const int rr = idx >> 5, cq = idx & 31;  // 32 lanes per row
        const int grow = bi * 128 + rr;
        const int gcol = bj * 128 + cq * 4;      // N%4==0 -> no partial vec
        if (grow < N_NODES && gcol < N_NODES) {
            const floatx4 v4 = *(const floatx4*)&smem[rr * SCR_STRIDE + cq * 4];
            __builtin_nontemporal_store(
                v4, (floatx4*)&sim[(unsigned)grow * N_NODES + gcol]);
        }
    }
    // ---- transposed orientation: column-gather from scratch, same stores ----
    if (bi != bj) {
        #pragma unroll
        for (int round = 0; round < 16; ++round) {
            const int idx = t + round * 256;
            const int rr = idx >> 5, cq = idx & 31;
            const int trow = bj * 128 + rr;
            const int tcol = bi * 128 + cq * 4;
            if (trow < N_NODES && tcol < N_NODES) {
                floatx4 v4;
                #pragma unroll
                for (int m = 0; m < 4; ++m)
                    v4[m] = smem[(cq * 4 + m) * SCR_STRIDE + rr];
                __builtin_nontemporal_store(
                    v4, (floatx4*)&sim[(unsigned)trow * N_NODES + tcol]);
            }
        }
    }
}

// ---------------------------------------------------------------------------
extern "C" void kernel_launch(void* const* d_in, const int* in_sizes, int n_in,
                              void* d_out, int out_size, void* d_ws, size_t ws_size,
                              hipStream_t stream)
{
    const float* x   = (const float*)d_in[0];
    const int*   ei  = (const int*)d_in[1];   // edge_index int32 [2,E]
    const float* dw  = (const float*)d_in[2];
    const float* db  = (const float*)d_in[3];
    const float* gw  = (const float*)d_in[4];
    const float* asv = (const float*)d_in[5];
    const float* adv = (const float*)d_in[6];
    const float* gb  = (const float*)d_in[7];

    float* out = (float*)d_out;
    float* sim = out;                                   // [N*N]
    float* emb = out + (size_t)N_NODES * N_NODES;       // [N*HID]

    // Scratch (all dead before sim_kernel):
    // z 640000 | a_src 10000 | a_dst 10000 | cnt 10000 | offs 10001 |
    // cursor 10000 | pad 1 | se (int2) 330000*2  => 1,350,002 * 4B ~= 5.4 MB
    const size_t need = 1350002u * sizeof(float);
    float* ws = (ws_size >= need) ? (float*)d_ws : out;  // fallback: carve sim
    float* z      = ws;
    float* a_src  = ws + 640000;
    float* a_dst  = ws + 650000;
    int*   cnt    = (int*)(ws + 660000);
    int*   offs   = (int*)(ws + 670000);    // 10001
    int*   cursor = (int*)(ws + 680001);
    intx2* se     = (intx2*)(ws + 690002);  // +1 pad for 8B alignment

    hipMemsetAsync(cnt, 0, N_NODES * sizeof(int), stream);

    // ---- fused cooperative graph pipeline, with separate-kernel fallback ----
    {
        const float* xa = x; const float* dwa = dw; const float* dba = db;
        const float* gwa = gw; const float* asa = asv; const float* ada = adv;
        const int* eia = ei; const float* gba = gb;
        float* za = z; float* asra = a_src; float* adsa = a_dst;
        int* cnta = cnt; int* offsa = offs; int* cura = cursor;
        intx2* sea = se; float* emba = emb;
        void* args[] = {&xa, &dwa, &dba, &gwa, &asa, &ada, &eia, &gba,
                        &za, &asra, &adsa, &cnta, &offsa, &cura, &sea, &emba};
        hipError_t err = hipLaunchCooperativeKernel(
            (const void*)fused_graph_kernel, dim3(COOP_BLOCKS), dim3(256),
            args, 0, stream);
        if (err != hipSuccess) {
            // fallback: stream-ordered separate kernels (bit-identical math)
            const int total_edges = E_EDGES + N_NODES;
            const int eb = (total_edges + 255) / 256;
            dense_gat_kernel<<<DG_BLOCKS, 256, 0, stream>>>(
                x, dw, db, gw, asv, adv, z, a_src, a_dst);
            count_kernel<<<eb, 256, 0, stream>>>(ei, cnt);
            scan_kernel<<<1, 256, 0, stream>>>(cnt, offs, cursor);
            scatter_kernel<<<eb, 256, 0, stream>>>(ei, a_src, a_dst, cursor, se);
            aggregate_kernel<<<(N_NODES * 64 + 255) / 256, 256, 0, stream>>>(
                offs, se, z, gb, emb);
        }
    }

    dim3 grid(79, 40);   // folded upper-triangle: 3160 blocks
    sim_kernel<<<grid, 256, 0, stream>>>(emb, sim);
}

// Round 5
// 501.929 us; speedup vs baseline: 1.8725x; 1.8725x over previous
//
#include <hip/hip_runtime.h>
#include <math.h>

#define N_NODES 10000
#define E_EDGES 320000
#define IN_DIM 128
#define EMB 128
#define HID 64
#define NEG_SLOPE 0.2f

#define DG_BLOCKS 625          // dense_gat: 625 * 16 rows = 10000
#define CNT_BLOCKS 665         // count rider blocks
#define TOTAL_EDGES (E_EDGES + N_NODES)

typedef __attribute__((ext_vector_type(8))) short short8;     // 8 bf16 (4 VGPR)
typedef __attribute__((ext_vector_type(4))) short short4_t;   // 4 bf16
typedef __attribute__((ext_vector_type(4))) float floatx4;    // 4 fp32
typedef __attribute__((ext_vector_type(2))) int   intx2;

// fp32 -> bf16 bits, round-to-nearest-even
__device__ __forceinline__ short f2bf(float f) {
    unsigned u = __float_as_uint(f);
    unsigned r = u + 0x7fffu + ((u >> 16) & 1u);
    return (short)(r >> 16);
}

__device__ __forceinline__ float sigmoidf_fast(float v) {
    return __builtin_amdgcn_rcpf(1.f + __expf(-v));
}

// ---------------------------------------------------------------------------
// Kernel A+count: blocks 0..624 run the dense+GAT GEMMs (R2 structure);
// blocks 625..1289 count edge in-degrees (independent outputs, no sync
// needed -> count hides completely under the GEMM work).
// ---------------------------------------------------------------------------
__global__ __launch_bounds__(256) void dense_gat_count_kernel(
    const float* __restrict__ x, const float* __restrict__ dw,
    const float* __restrict__ db, const float* __restrict__ gw,
    const float* __restrict__ asv, const float* __restrict__ adv,
    const int* __restrict__ ei,
    float* __restrict__ z, float* __restrict__ a_src, float* __restrict__ a_dst,
    int* __restrict__ cnt)
{
    __shared__ float smem[8192];         // 32 KB
    const int t = threadIdx.x;
    const int b = blockIdx.x;

    if (b >= DG_BLOCKS) {                // ---- count rider ----
        const int nth = CNT_BLOCKS * 256;
        for (int e = (b - DG_BLOCKS) * 256 + t; e < TOTAL_EDGES; e += nth) {
            int s, d;
            if (e < E_EDGES) { s = ei[e]; d = ei[E_EDGES + e]; }
            else             { s = d = e - E_EDGES; }
            if ((unsigned)s >= N_NODES || (unsigned)d >= N_NODES) continue;
            atomicAdd(&cnt[d], 1);
        }
        return;
    }

    float* const xs  = smem;             // [16][128]
    float* const hs  = smem + 2048;      // [16][128]
    float* const wsm = smem + 4096;      // [32*128] / [64*64]
    const int row0 = b * 16;             // 10000 % 16 == 0

    #pragma unroll
    for (int r = 0; r < 2; ++r) {
        const int idx = t + r * 256;           // 0..511 float4 slots
        const int row = idx >> 5, c4 = idx & 31;
        *(floatx4*)&xs[row * 128 + c4 * 4] =
            *(const floatx4*)&x[(row0 + row) * IN_DIM + c4 * 4];
    }

    // GEMM1: col = t&127, rows (t>>7)*8 .. +8
    const int col = t & 127, rb = (t >> 7) * 8;
    float acc[8];
    {
        const float bias = db[col];
        #pragma unroll
        for (int r = 0; r < 8; ++r) acc[r] = bias;
    }
    for (int ch = 0; ch < 4; ++ch) {
        __syncthreads();                       // xs ready (ch=0) / wsm reads done
        #pragma unroll
        for (int r = 0; r < 4; ++r) {          // stage dw[ch*32..+32][0..128]
            const int idx = t + r * 256;
            const int row = idx >> 5, c4 = idx & 31;
            *(floatx4*)&wsm[row * 128 + c4 * 4] =
                *(const floatx4*)&dw[(ch * 32 + row) * EMB + c4 * 4];
        }
        __syncthreads();
        #pragma unroll
        for (int jg = 0; jg < 8; ++jg) {
            const int jb = jg * 4;
            floatx4 xr[8];
            #pragma unroll
            for (int r = 0; r < 8; ++r)
                xr[r] = *(const floatx4*)&xs[(rb + r) * 128 + ch * 32 + jb];
            float wv[4];
            #pragma unroll
            for (int k = 0; k < 4; ++k) wv[k] = wsm[(jb + k) * 128 + col];
            #pragma unroll
            for (int k = 0; k < 4; ++k)
                #pragma unroll
                for (int r = 0; r < 8; ++r) acc[r] = fmaf(xr[r][k], wv[k], acc[r]);
        }
    }
    #pragma unroll
    for (int r = 0; r < 8; ++r) hs[(rb + r) * 128 + col] = fmaxf(acc[r], 0.f);

    // GEMM2: col2 = t&63, rows (t>>6)*4 .. +4
    const int col2 = t & 63, rb2 = (t >> 6) * 4;
    float acc2[4] = {0.f, 0.f, 0.f, 0.f};
    for (int ch = 0; ch < 2; ++ch) {
        __syncthreads();                       // hs ready / wsm reads done
        #pragma unroll
        for (int r = 0; r < 4; ++r) {          // stage gw[ch*64..+64][0..64]
            const int idx = t + r * 256;
            const int row = idx >> 4, c4 = idx & 15;
            *(floatx4*)&wsm[row * 64 + c4 * 4] =
                *(const floatx4*)&gw[(ch * 64 + row) * HID + c4 * 4];
        }
        __syncthreads();
        #pragma unroll
        for (int kg = 0; kg < 16; ++kg) {
            const int kb = kg * 4;
            floatx4 hr[4];
            #pragma unroll
            for (int r = 0; r < 4; ++r)
                hr[r] = *(const floatx4*)&hs[(rb2 + r) * 128 + ch * 64 + kb];
            float gv[4];
            #pragma unroll
            for (int k = 0; k < 4; ++k) gv[k] = wsm[(kb + k) * 64 + col2];
            #pragma unroll
            for (int k = 0; k < 4; ++k)
                #pragma unroll
                for (int r = 0; r < 4; ++r) acc2[r] = fmaf(hr[r][k], gv[k], acc2[r]);
        }
    }

    // store z + fused attention dot products (wave holds full row of 64 cols)
    const float as_c = asv[col2], ad_c = adv[col2];
    #pragma unroll
    for (int r = 0; r < 4; ++r) {
        z[(row0 + rb2 + r) * HID + col2] = acc2[r];
        float ps = acc2[r] * as_c;
        float pd = acc2[r] * ad_c;
        #pragma unroll
        for (int off = 32; off > 0; off >>= 1) {
            ps += __shfl_down(ps, off, 64);
            pd += __shfl_down(pd, off, 64);
        }
        if ((t & 63) == 0) {
            a_src[row0 + rb2 + r] = ps;
            a_dst[row0 + rb2 + r] = pd;
        }
    }
}

// ---------------------------------------------------------------------------
// scan: single block, 1024 threads, 10 items each (10240 >= 10000).
// ---------------------------------------------------------------------------
__global__ __launch_bounds__(1024) void scan_kernel(
    const int* __restrict__ cnt, int* __restrict__ offs, int* __restrict__ cursor)
{
    __shared__ int part[1024];
    const int t = threadIdx.x;
    const int base = t * 10;
    int vals[10];
    int local = 0;
    #pragma unroll
    for (int i = 0; i < 10; ++i) {
        const int idx = base + i;
        const int c = (idx < N_NODES) ? cnt[idx] : 0;
        vals[i] = c;
        local += c;
    }
    part[t] = local;
    __syncthreads();
    for (int off = 1; off < 1024; off <<= 1) {  // Hillis-Steele inclusive
        const int v = (t >= off) ? part[t - off] : 0;
        __syncthreads();
        part[t] += v;
        __syncthreads();
    }
    int running = (t == 0) ? 0 : part[t - 1];   // exclusive base
    #pragma unroll
    for (int i = 0; i < 10; ++i) {
        const int idx = base + i;
        if (idx < N_NODES) { offs[idx] = running; cursor[idx] = running; }
        running += vals[i];
    }
    if (t == 1023) offs[N_NODES] = running;
}

__global__ __launch_bounds__(256) void scatter_kernel(
    const int* __restrict__ ei, const float* __restrict__ a_src,
    const float* __restrict__ a_dst, int* __restrict__ cursor,
    intx2* __restrict__ se)
{
    const int e = blockIdx.x * blockDim.x + threadIdx.x;
    if (e >= TOTAL_EDGES) return;
    int s, d;
    if (e < E_EDGES) { s = ei[e]; d = ei[E_EDGES + e]; }
    else             { s = d = e - E_EDGES; }
    if ((unsigned)s >= N_NODES || (unsigned)d >= N_NODES) return;
    float v = a_src[s] + a_dst[d];
    v = (v > 0.f) ? v : NEG_SLOPE * v;
    const float w = __expf(v);          // max-shift skipped: |v| small, fp32 safe
    const int pos = atomicAdd(&cursor[d], 1);
    intx2 p;
    p[0] = s;
    p[1] = __float_as_int(w);
    se[pos] = p;                        // one 8B record
}

// one wave per node; 4 edges in flight (16 lanes x float4 each) -> dependent
// load chain cut 4x. z row reads stay 256B coalesced.
__global__ __launch_bounds__(256) void aggregate_kernel(
    const int* __restrict__ offs, const intx2* __restrict__ se,
    const float* __restrict__ z, const float* __restrict__ gb,
    float* __restrict__ emb)
{
    const int wid  = (blockIdx.x * blockDim.x + threadIdx.x) >> 6;
    const int lane = threadIdx.x & 63;
    if (wid >= N_NODES) return;
    const int g  = lane >> 4;            // edge subgroup 0..3
    const int c4 = (lane & 15) * 4;      // feature slot
    const int beg = offs[wid], end = offs[wid + 1];
    floatx4 acc = {0.f, 0.f, 0.f, 0.f};
    float sw = 0.f;
    for (int i = beg + g; i < end; i += 4) {
        const intx2 p = se[i];                                // broadcast in group
        const floatx4 zv = *(const floatx4*)&z[p[0] * HID + c4];
        const float w = __int_as_float(p[1]);
        acc += zv * w;
        sw  += w;
    }
    #pragma unroll
    for (int off = 16; off <= 32; off <<= 1) {
        #pragma unroll
        for (int k = 0; k < 4; ++k) acc[k] += __shfl_xor(acc[k], off, 64);
        sw += __shfl_xor(sw, off, 64);
    }
    if (g == 0) {
        const floatx4 gv = *(const floatx4*)&gb[c4];
        floatx4 r;
        #pragma unroll
        for (int k = 0; k < 4; ++k) r[k] = acc[k] / sw + gv[k];
        *(floatx4*)&emb[wid * HID + c4] = r;   // every node has a self loop
    }
}

// ---------------------------------------------------------------------------
// Kernel D: sim = sigmoid(emb @ emb^T). FULL 79x79 grid, normal-orientation
// stores only (the fold was measured neutral: MFMA is ~5 us total, and the
// transposed path cost 4-way LDS gathers + short store runs). 256 thr,
// 4 waves; wave w owns row-fragments {w, w+4} (INTERLEAVED) so both epilogue
// halves keep every wave busy. Epilogue: sigmoid half-tile into a [64][133]
// f32 scratch aliased over the staging buffers, then 512B-contiguous NT
// float4 runs. LDS = 36864 B -> 4 blocks/CU (was 2). Per-element arithmetic
// identical to R2 (same MFMA K-order) -> absmax unchanged.
// ---------------------------------------------------------------------------
#define SROW 72
#define SCR 133
__global__ __launch_bounds__(256, 4) void sim_kernel(
    const float* __restrict__ emb, float* __restrict__ sim)
{
    __shared__ float smem[9216];                   // 36864 B
    short* const As = (short*)smem;                // [128*72] bf16
    short* const Bs = (short*)smem + 128 * SROW;   // [128*72] bf16
    float* const scr = smem;                       // [64][133] f32 (aliased)
    const int t    = threadIdx.x;
    const int lane = t & 63;
    const int wave = t >> 6;                 // 0..3
    const int l15  = lane & 15;
    const int quad = lane >> 4;              // 0..3

    const int bi = blockIdx.y;               // row tile
    const int bj = blockIdx.x;               // col tile

    // ---- stage both row-tiles as bf16 into LDS (8 rounds x 256 thr) ----
    #pragma unroll
    for (int round = 0; round < 8; ++round) {
        const int idx = t + round * 256;     // 0..2047
        const int row = idx >> 4, c4 = idx & 15;
        int gr = bi * 128 + row; if (gr > N_NODES - 1) gr = N_NODES - 1;
        int gc = bj * 128 + row; if (gc > N_NODES - 1) gc = N_NODES - 1;
        const floatx4 a = *(const floatx4*)&emb[gr * HID + c4 * 4];
        const floatx4 b = *(const floatx4*)&emb[gc * HID + c4 * 4];
        short4_t sa, sb;
        #pragma unroll
        for (int j = 0; j < 4; ++j) { sa[j] = f2bf(a[j]); sb[j] = f2bf(b[j]); }
        *(short4_t*)&As[row * SROW + c4 * 4] = sa;
        *(short4_t*)&Bs[row * SROW + c4 * 4] = sb;
    }
    __syncthreads();

    // ---- fragments + MFMA: wave owns rows (ti*4+wave)*16 .. +16, all cols --
    short8 afrag[2][2];
    #pragma unroll
    for (int ti = 0; ti < 2; ++ti)
        #pragma unroll
        for (int ks = 0; ks < 2; ++ks)
            afrag[ti][ks] = *(const short8*)&As[((ti * 4 + wave) * 16 + l15) * SROW +
                                                ks * 32 + quad * 8];

    floatx4 acc[2][8];
    const floatx4 zero = {0.f, 0.f, 0.f, 0.f};
    #pragma unroll
    for (int ti = 0; ti < 2; ++ti)
        #pragma unroll
        for (int tj = 0; tj < 8; ++tj) acc[ti][tj] = zero;

    #pragma unroll
    for (int tj = 0; tj < 8; ++tj) {
        const short8 bf0 = *(const short8*)&Bs[(tj * 16 + l15) * SROW + quad * 8];
        const short8 bf1 = *(const short8*)&Bs[(tj * 16 + l15) * SROW + 32 + quad * 8];
        #pragma unroll
        for (int ti = 0; ti < 2; ++ti) {
            acc[ti][tj] = __builtin_amdgcn_mfma_f32_16x16x32_bf16(
                afrag[ti][0], bf0, acc[ti][tj], 0, 0, 0);
            acc[ti][tj] = __builtin_amdgcn_mfma_f32_16x16x32_bf16(
                afrag[ti][1], bf1, acc[ti][tj], 0, 0, 0);
        }
    }
    __syncthreads();   // all LDS tile reads done before scratch reuse

    // ---- epilogue: two 64-row halves; EVERY wave active in each phase ----
    #pragma unroll
    for (int h = 0; h < 2; ++h) {
        // wave's fragment ti=h covers rows-in-half wave*16 .. +16
        // C/D layout: row = quad*4+reg (within 16), col = l15
        #pragma unroll
        for (int reg = 0; reg < 4; ++reg)
            #pragma unroll
            for (int tj = 0; tj < 8; ++tj)
                scr[(wave * 16 + quad * 4 + reg) * SCR + tj * 16 + l15] =
                    sigmoidf_fast(acc[h][tj][reg]);
        __syncthreads();

        // 64 rows x 128 cols, 512B contiguous NT float4 runs
        #pragma unroll
        for (int round = 0; round < 8; ++round) {
            const int idx = t + round * 256;         // 0..2047
            const int rr = idx >> 5, cq = idx & 31;
            const int grow = bi * 128 + (h * 4 + (rr >> 4)) * 16 + (rr & 15);
            const int gcol = bj * 128 + cq * 4;
            if (grow < N_NODES && gcol < N_NODES) {
                const floatx4 v4 = *(const floatx4*)&scr[rr * SCR + cq * 4];
                __builtin_nontemporal_store(
                    v4, (floatx4*)&sim[(unsigned)grow * N_NODES + gcol]);
            }
        }
        __syncthreads();    // scratch reads done before next half overwrites
    }
}

// ---------------------------------------------------------------------------
extern "C" void kernel_launch(void* const* d_in, const int* in_sizes, int n_in,
                              void* d_out, int out_size, void* d_ws, size_t ws_size,
                              hipStream_t stream)
{
    const float* x   = (const float*)d_in[0];
    const int*   ei  = (const int*)d_in[1];   // edge_index int32 [2,E]
    const float* dw  = (const float*)d_in[2];
    const float* db  = (const float*)d_in[3];
    const float* gw  = (const float*)d_in[4];
    const float* asv = (const float*)d_in[5];
    const float* adv = (const float*)d_in[6];
    const float* gb  = (const float*)d_in[7];

    float* out = (float*)d_out;
    float* sim = out;                                   // [N*N]
    float* emb = out + (size_t)N_NODES * N_NODES;       // [N*HID]

    // Scratch (all dead before sim_kernel):
    // z 640000 | a_src 10000 | a_dst 10000 | cnt 10000 | offs 10001 |
    // cursor 10000 | pad 1 | se (int2) 330000*2  => 1,350,002 * 4B ~= 5.4 MB
    const size_t need = 1350002u * sizeof(float);
    float* ws = (ws_size >= need) ? (float*)d_ws : out;  // fallback: carve sim
    float* z      = ws;
    float* a_src  = ws + 640000;
    float* a_dst  = ws + 650000;
    int*   cnt    = (int*)(ws + 660000);
    int*   offs   = (int*)(ws + 670000);    // 10001
    int*   cursor = (int*)(ws + 680001);
    intx2* se     = (intx2*)(ws + 690002);  // +1 pad for 8B alignment

    hipMemsetAsync(cnt, 0, N_NODES * sizeof(int), stream);

    // dense_gat (625 blocks) + count rider (665 blocks), one launch
    dense_gat_count_kernel<<<DG_BLOCKS + CNT_BLOCKS, 256, 0, stream>>>(
        x, dw, db, gw, asv, adv, ei, z, a_src, a_dst, cnt);

    scan_kernel<<<1, 1024, 0, stream>>>(cnt, offs, cursor);

    const int eb = (TOTAL_EDGES + 255) / 256;
    scatter_kernel<<<eb, 256, 0, stream>>>(ei, a_src, a_dst, cursor, se);
    aggregate_kernel<<<(N_NODES * 64 + 255) / 256, 256, 0, stream>>>(
        offs, se, z, gb, emb);

    dim3 grid(79, 79);   // full grid, normal-orientation stores only
    sim_kernel<<<grid, 256, 0, stream>>>(emb, sim);
}